// Round 23
// baseline (111.721 us; speedup 1.0000x reference)
//
// Round 23: r17 merged-prep2 base + (a) router 8 b-rows/block via bf16 LDS
// staging (rw traffic 64->32 MB), (b) 4-byte packed edge entries
// (bf16 val | u16 row): halves binning scatter, packed footprint, gather meta.
#include <hip/hip_runtime.h>
#include <math.h>

namespace {

constexpr int B     = 512;
constexpr int IN    = 2048;
constexpr int HID   = 4096;
constexpr int NNZ_W = 83886;
constexpr int NNZ_R = 167772;
constexpr int NTOT  = NNZ_W + 2 * NNZ_R;   // 419430 edges across W,R,P
constexpr int NCOLS = 3 * HID;             // global column id = mat*HID + col
constexpr int SLOT  = 128;                 // per-column bucket capacity
constexpr float DT  = 0.1f;

constexpr int TRX   = 256;                 // x-transpose tiles
constexpr int TRH   = 512;                 // h-transpose tiles
constexpr int RTR   = 64;                  // router blocks (8 b-rows each)
constexpr int BIN   = (NTOT + 511) / 512;  // 820 binning blocks (LAST)
constexpr int PREP2 = TRX + TRH + RTR + BIN;

typedef float f4 __attribute__((ext_vector_type(4)));
typedef unsigned short us8 __attribute__((ext_vector_type(8)));
typedef unsigned int u4 __attribute__((ext_vector_type(4)));

struct f8 { f4 lo, hi; };

__device__ __forceinline__ float bf2f(unsigned short u) {
  return __uint_as_float((unsigned int)u << 16);
}
__device__ __forceinline__ unsigned short f2bf(float f) {  // round-nearest-even
  unsigned int u = __float_as_uint(f);
  u += 0x7FFFu + ((u >> 16) & 1u);
  return (unsigned short)(u >> 16);
}

// ---------------------------------------------------------------------------
// prep2_k, 512 threads, roles by blockIdx.x — r17 ORDER (binning last):
//  [0,TRX)                transpose x[B][IN]  -> xTb (bf16)
//  [TRX,TRX+TRH)          transpose h[B][HID] -> hT (f32) + hTb (bf16)
//  [TRX+TRH,+RTR)         router: 8 b-rows/block, bf16 LDS staging
//  [TRX+TRH+RTR,+BIN)     binning -> 4B packed entries (bf16 val | u16 row)
// ---------------------------------------------------------------------------
__global__ void prep2_k(const float* __restrict__ x, unsigned short* __restrict__ xTb,
                        const float* __restrict__ h, float* __restrict__ hT,
                        unsigned short* __restrict__ hTb,
                        const float* __restrict__ rw, const float* __restrict__ rb,
                        float* __restrict__ rgT,
                        const int* __restrict__ Wc, const int* __restrict__ Rc,
                        const int* __restrict__ Pc, const int* __restrict__ Wr,
                        const int* __restrict__ Rr, const int* __restrict__ Pr,
                        const float* __restrict__ Wv, const float* __restrict__ Rv,
                        const float* __restrict__ Pv, int* __restrict__ cnt,
                        unsigned int* __restrict__ packed) {
  __shared__ float sh[4 * IN];            // 32 KB (router reuses as bf16[8][IN])
  const int blk = blockIdx.x;
  const int tid = threadIdx.x;

  if (blk < TRX + TRH) {                  // --- transpose roles ---
    const bool isX = blk < TRX;
    const float* src; int C, tb;
    if (isX) { src = x; C = IN;  tb = blk; }
    else     { src = h; C = HID; tb = blk - TRX; }
    const int tx_n = C / 64;
    const int bx = (tb % tx_n) * 64;
    const int by = (tb / tx_n) * 64;
    const int tx = tid & 63;
    const int ty = tid >> 6;              // 0..7
    for (int i = ty; i < 64; i += 8)
      sh[i * 65 + tx] = src[(size_t)(by + i) * C + bx + tx];
    __syncthreads();
    for (int i = ty; i < 64; i += 8) {
      const float v = sh[tx * 65 + i];
      const size_t di = (size_t)(bx + i) * B + by + tx;
      if (isX) xTb[di] = f2bf(v);
      else     { hT[di] = v; hTb[di] = f2bf(v); }
    }
  } else if (blk < TRX + TRH + RTR) {     // --- router: 8 b-rows per block ---
    unsigned short* shb = (unsigned short*)sh;       // bf16[8][IN] = 32 KB
    const int b0 = (blk - TRX - TRH) * 8;
    for (int k = tid; k < 8 * IN; k += 512)
      shb[k] = f2bf(x[(size_t)b0 * IN + k]);
    __syncthreads();
    const int wave = tid >> 6;
    const int lane = tid & 63;
#pragma unroll
    for (int j = 0; j < 8; ++j) {
      const int o = wave * 8 + j;
      const float* w = rw + (size_t)o * IN;
      float s[8] = {0.f, 0.f, 0.f, 0.f, 0.f, 0.f, 0.f, 0.f};
      for (int i = 0; i < IN / 64; ++i) {            // 32 iters
        const float wv = w[lane + 64 * i];           // coalesced 256B
#pragma unroll
        for (int r = 0; r < 8; ++r)
          s[r] += bf2f(shb[r * IN + lane + 64 * i]) * wv;
      }
#pragma unroll
      for (int r = 0; r < 8; ++r) {
#pragma unroll
        for (int d = 1; d < 64; d <<= 1) s[r] += __shfl_xor(s[r], d);
      }
      if (lane == 0) {
        const float bias = rb[o];
#pragma unroll
        for (int r = 0; r < 8; ++r)
          rgT[o * B + b0 + r] = 1.f / (1.f + expf(-(s[r] + bias)));
      }
    }
  } else {                                // --- binning (last), 4B entries ---
    const int i = (blk - TRX - TRH - RTR) * 512 + tid;
    if (i >= NTOT) return;
    int gc, r; float v;
    if (i < NNZ_W)              { gc = Wc[i];                 r = Wr[i]; v = Wv[i]; }
    else if (i < NNZ_W + NNZ_R) { int j = i - NNZ_W;          gc = HID + Rc[j];     r = Rr[j]; v = Rv[j]; }
    else                        { int j = i - NNZ_W - NNZ_R; gc = 2 * HID + Pc[j]; r = Pr[j]; v = Pv[j]; }
    const int p = atomicAdd(&cnt[gc], 1);
    packed[(size_t)gc * SLOT + p] = ((unsigned int)f2bf(v) << 16) | (unsigned int)(r & 0xFFFF);
  }
}

// ---------------------------------------------------------------------------
// Full-column bf16 gather, 4B meta entries: 8-batch meta = two uint4 loads.
// ---------------------------------------------------------------------------
__device__ __forceinline__ f8 gather_col_bf8(const unsigned short* __restrict__ srcb,
                                             const unsigned int* __restrict__ packed,
                                             int gc, int n, int boff, float bias) {
  f4 a0; a0.x = bias; a0.y = bias; a0.z = bias; a0.w = bias;
  f4 a1 = a0;
  const unsigned int* ep = packed + (size_t)gc * SLOT;
  int i = 0;
  for (; i + 8 <= n; i += 8) {
    const u4 e0 = *(const u4*)(ep + i);
    const u4 e1 = *(const u4*)(ep + i + 4);
    unsigned int e[8] = {e0.x, e0.y, e0.z, e0.w, e1.x, e1.y, e1.z, e1.w};
    us8 s[8];
#pragma unroll
    for (int j = 0; j < 8; ++j)
      s[j] = *(const us8*)(srcb + (size_t)(e[j] & 0xFFFFu) * B + boff);
#pragma unroll
    for (int j = 0; j < 8; ++j) {
      const float v = bf2f((unsigned short)(e[j] >> 16));
      a0.x += v * bf2f(s[j][0]); a0.y += v * bf2f(s[j][1]);
      a0.z += v * bf2f(s[j][2]); a0.w += v * bf2f(s[j][3]);
      a1.x += v * bf2f(s[j][4]); a1.y += v * bf2f(s[j][5]);
      a1.z += v * bf2f(s[j][6]); a1.w += v * bf2f(s[j][7]);
    }
  }
  for (; i < n; ++i) {
    const unsigned int e = ep[i];
    const us8 s = *(const us8*)(srcb + (size_t)(e & 0xFFFFu) * B + boff);
    const float v = bf2f((unsigned short)(e >> 16));
    a0.x += v * bf2f(s[0]); a0.y += v * bf2f(s[1]);
    a0.z += v * bf2f(s[2]); a0.w += v * bf2f(s[3]);
    a1.x += v * bf2f(s[4]); a1.y += v * bf2f(s[5]);
    a1.z += v * bf2f(s[6]); a1.w += v * bf2f(s[7]);
  }
  f8 r; r.lo = a0; r.hi = a1;
  return r;
}

// Epilogue: block's [4 c][512 b] tile -> row-major out (one f4/thread x 2 rows).
__device__ __forceinline__ void store_tile_T(float* __restrict__ tile,  // [4][512]
                                             const f8 v, int wave, int lane,
                                             int c0, float* __restrict__ out) {
  ((f4*)tile)[wave * 128 + lane * 2 + 0] = v.lo;
  ((f4*)tile)[wave * 128 + lane * 2 + 1] = v.hi;
  __syncthreads();
  const int t = threadIdx.x;              // 0..255
#pragma unroll
  for (int r = 0; r < 2; ++r) {
    const int b = r * 256 + t;
    f4 o;
    o.x = tile[0 * 512 + b];
    o.y = tile[1 * 512 + b];
    o.z = tile[2 * 512 + b];
    o.w = tile[3 * 512 + b];
    *(f4*)(out + (size_t)b * HID + c0) = o;
  }
}

// ---------------------------------------------------------------------------
// Fused: one wave per column; fp32 hT carry (r17 numerics).
// ---------------------------------------------------------------------------
__global__ void fused_gc_k(const unsigned short* __restrict__ xTb,
                           const unsigned short* __restrict__ hTb,
                           const float* __restrict__ hT,
                           const unsigned int* __restrict__ packed, const int* __restrict__ cnt,
                           const float* __restrict__ rgT,
                           const float* __restrict__ gate, const float* __restrict__ tau,
                           const float* __restrict__ wb, const float* __restrict__ rb,
                           float* __restrict__ out_h, unsigned short* __restrict__ hnb) {
  __shared__ float tile[4 * 512];
  const int wave = threadIdx.x >> 6, lane = threadIdx.x & 63;
  const int c0 = blockIdx.x * 4;
  const int c = c0 + wave;
  const int boff = lane * 8;

  const f8 sens = gather_col_bf8(xTb, packed, c, cnt[c], boff, wb[c]);
  const f8 rec  = gather_col_bf8(hTb, packed, HID + c, cnt[HID + c], boff, rb[c]);

  const float* rg = rgT + (size_t)(c >> 6) * B + boff;
  const f4 m0 = *(const f4*)rg;
  const f4 m1 = *(const f4*)(rg + 4);
  const f4 g0 = *(const f4*)(gate + boff);
  const f4 g1 = *(const f4*)(gate + boff + 4);
  const float* hpp = hT + (size_t)c * B + boff;
  const f4 hp0 = *(const f4*)hpp;
  const f4 hp1 = *(const f4*)(hpp + 4);
  const float k = DT / tau[c];

  f8 hn;
  hn.lo.x = hp0.x + g0.x * (tanhf(sens.lo.x * m0.x + rec.lo.x) - hp0.x) * k;
  hn.lo.y = hp0.y + g0.y * (tanhf(sens.lo.y * m0.y + rec.lo.y) - hp0.y) * k;
  hn.lo.z = hp0.z + g0.z * (tanhf(sens.lo.z * m0.z + rec.lo.z) - hp0.z) * k;
  hn.lo.w = hp0.w + g0.w * (tanhf(sens.lo.w * m0.w + rec.lo.w) - hp0.w) * k;
  hn.hi.x = hp1.x + g1.x * (tanhf(sens.hi.x * m1.x + rec.hi.x) - hp1.x) * k;
  hn.hi.y = hp1.y + g1.y * (tanhf(sens.hi.y * m1.y + rec.hi.y) - hp1.y) * k;
  hn.hi.z = hp1.z + g1.z * (tanhf(sens.hi.z * m1.z + rec.hi.z) - hp1.z) * k;
  hn.hi.w = hp1.w + g1.w * (tanhf(sens.hi.w * m1.w + rec.hi.w) - hp1.w) * k;

  us8 hb;
  hb[0] = f2bf(hn.lo.x); hb[1] = f2bf(hn.lo.y); hb[2] = f2bf(hn.lo.z); hb[3] = f2bf(hn.lo.w);
  hb[4] = f2bf(hn.hi.x); hb[5] = f2bf(hn.hi.y); hb[6] = f2bf(hn.hi.z); hb[7] = f2bf(hn.hi.w);
  *(us8*)(hnb + (size_t)c * B + boff) = hb;   // cached: pred's hot source

  store_tile_T(tile, hn, wave, lane, c0, out_h);
}

// ---------------------------------------------------------------------------
// Prediction: full-column waves from hnb, writes out_p.
// ---------------------------------------------------------------------------
__global__ void pred_k(const unsigned short* __restrict__ hnb,
                       const unsigned int* __restrict__ packed, const int* __restrict__ cnt,
                       const float* __restrict__ pb, float* __restrict__ out_p) {
  __shared__ float tile[4 * 512];
  const int wave = threadIdx.x >> 6, lane = threadIdx.x & 63;
  const int c0 = blockIdx.x * 4;
  const int c = c0 + wave;
  const int boff = lane * 8;
  const f8 p = gather_col_bf8(hnb, packed, 2 * HID + c, cnt[2 * HID + c], boff, pb[c]);
  store_tile_T(tile, p, wave, lane, c0, out_p);
}

}  // namespace

extern "C" void kernel_launch(void* const* d_in, const int* in_sizes, int n_in,
                              void* d_out, int out_size, void* d_ws, size_t ws_size,
                              hipStream_t stream) {
  const float* x        = (const float*)d_in[0];
  const float* h_prev   = (const float*)d_in[1];
  const float* gate     = (const float*)d_in[2];
  const float* W_vals   = (const float*)d_in[3];
  const float* W_bias   = (const float*)d_in[4];
  const float* R_vals   = (const float*)d_in[5];
  const float* R_bias   = (const float*)d_in[6];
  const float* P_vals   = (const float*)d_in[7];
  const float* P_bias   = (const float*)d_in[8];
  const float* router_w = (const float*)d_in[9];
  const float* router_b = (const float*)d_in[10];
  const float* tau      = (const float*)d_in[11];
  const int* W_rows = (const int*)d_in[12];
  const int* W_cols = (const int*)d_in[13];
  const int* R_rows = (const int*)d_in[14];
  const int* R_cols = (const int*)d_in[15];
  const int* P_rows = (const int*)d_in[16];
  const int* P_cols = (const int*)d_in[17];

  float* ws = (float*)d_ws;
  unsigned short* xTb = (unsigned short*)ws;                      // [IN][B]  bf16  2 MB
  float*  hT     = ws + (size_t)IN * B / 2;                       // [HID][B] f32   8 MB
  unsigned short* hTb = (unsigned short*)(hT + (size_t)HID * B);  // [HID][B] bf16  4 MB
  float*  rgT    = (float*)(hTb + (size_t)HID * B);               // [64][B]  f32
  unsigned short* hnb = (unsigned short*)(rgT + 64 * B);          // [HID][B] bf16  4 MB
  unsigned int* packed = (unsigned int*)(hnb + (size_t)HID * B);  // [NCOLS*SLOT] u32 6.3 MB
  int*    cnt    = (int*)(packed + (size_t)NCOLS * SLOT);         // [NCOLS]  48 KB

  float* out_h = (float*)d_out;
  float* out_p = out_h + (size_t)B * HID;

  // 1. Zero bucket counters (stream-ordered before binning atomics).
  hipMemsetAsync(cnt, 0, NCOLS * sizeof(int), stream);

  // 2. Merged prep (r17 role order): transposes, router, binning last.
  prep2_k<<<PREP2, 512, 0, stream>>>(x, xTb, h_prev, hT, hTb,
                                     router_w, router_b, rgT,
                                     W_cols, R_cols, P_cols,
                                     W_rows, R_rows, P_rows,
                                     W_vals, R_vals, P_vals, cnt, packed);

  // 3. Fused gather + integrate -> out_h (direct) + hnb.
  fused_gc_k<<<HID / 4, 256, 0, stream>>>(xTb, hTb, hT, packed, cnt, rgT,
                                          gate, tau, W_bias, R_bias, out_h, hnb);

  // 4. Prediction gather -> out_p (direct).
  pred_k<<<HID / 4, 256, 0, stream>>>(hnb, packed, cnt, P_bias, out_p);
}

// Round 24
// 93.639 us; speedup vs baseline: 1.1931x; 1.1931x over previous
//
// Round 24: r17-exact (router = 4-row fp32-LDS, 52 VGPR) + ONLY the 4-byte
// packed edge entries (bf16 val | u16 row) — single-variable A/B vs r17.
#include <hip/hip_runtime.h>
#include <math.h>

namespace {

constexpr int B     = 512;
constexpr int IN    = 2048;
constexpr int HID   = 4096;
constexpr int NNZ_W = 83886;
constexpr int NNZ_R = 167772;
constexpr int NTOT  = NNZ_W + 2 * NNZ_R;   // 419430 edges across W,R,P
constexpr int NCOLS = 3 * HID;             // global column id = mat*HID + col
constexpr int SLOT  = 128;                 // per-column bucket capacity
constexpr float DT  = 0.1f;

constexpr int TRX   = 256;                 // x-transpose tiles
constexpr int TRH   = 512;                 // h-transpose tiles
constexpr int RTR   = 128;                 // router blocks (4 b-rows each — r17)
constexpr int BIN   = (NTOT + 511) / 512;  // 820 binning blocks (LAST)
constexpr int PREP2 = TRX + TRH + RTR + BIN;

typedef float f4 __attribute__((ext_vector_type(4)));
typedef unsigned short us8 __attribute__((ext_vector_type(8)));
typedef unsigned int u4 __attribute__((ext_vector_type(4)));

struct f8 { f4 lo, hi; };

__device__ __forceinline__ float bf2f(unsigned short u) {
  return __uint_as_float((unsigned int)u << 16);
}
__device__ __forceinline__ unsigned short f2bf(float f) {  // round-nearest-even
  unsigned int u = __float_as_uint(f);
  u += 0x7FFFu + ((u >> 16) & 1u);
  return (unsigned short)(u >> 16);
}

// ---------------------------------------------------------------------------
// prep2_k, 512 threads, roles by blockIdx.x — r17 ORDER and r17 router:
//  [0,TRX)                transpose x[B][IN]  -> xTb (bf16)
//  [TRX,TRX+TRH)          transpose h[B][HID] -> hT (f32) + hTb (bf16)
//  [TRX+TRH,+RTR)         router (4 b-rows/block, fp32 LDS — r17-exact)
//  [TRX+TRH+RTR,+BIN)     binning -> 4B packed entries (bf16 val | u16 row)
// ---------------------------------------------------------------------------
__global__ void prep2_k(const float* __restrict__ x, unsigned short* __restrict__ xTb,
                        const float* __restrict__ h, float* __restrict__ hT,
                        unsigned short* __restrict__ hTb,
                        const float* __restrict__ rw, const float* __restrict__ rb,
                        float* __restrict__ rgT,
                        const int* __restrict__ Wc, const int* __restrict__ Rc,
                        const int* __restrict__ Pc, const int* __restrict__ Wr,
                        const int* __restrict__ Rr, const int* __restrict__ Pr,
                        const float* __restrict__ Wv, const float* __restrict__ Rv,
                        const float* __restrict__ Pv, int* __restrict__ cnt,
                        unsigned int* __restrict__ packed) {
  __shared__ float sh[4 * IN];            // 32 KB
  const int blk = blockIdx.x;
  const int tid = threadIdx.x;

  if (blk < TRX + TRH) {                  // --- transpose roles ---
    const bool isX = blk < TRX;
    const float* src; int C, tb;
    if (isX) { src = x; C = IN;  tb = blk; }
    else     { src = h; C = HID; tb = blk - TRX; }
    const int tx_n = C / 64;
    const int bx = (tb % tx_n) * 64;
    const int by = (tb / tx_n) * 64;
    const int tx = tid & 63;
    const int ty = tid >> 6;              // 0..7
    for (int i = ty; i < 64; i += 8)
      sh[i * 65 + tx] = src[(size_t)(by + i) * C + bx + tx];
    __syncthreads();
    for (int i = ty; i < 64; i += 8) {
      const float v = sh[tx * 65 + i];
      const size_t di = (size_t)(bx + i) * B + by + tx;
      if (isX) xTb[di] = f2bf(v);
      else     { hT[di] = v; hTb[di] = f2bf(v); }
    }
  } else if (blk < TRX + TRH + RTR) {     // --- router: 4 b-rows per block ---
    const int b0 = (blk - TRX - TRH) * 4;
    for (int k = tid; k < 4 * IN; k += 512) sh[k] = x[(size_t)b0 * IN + k];
    __syncthreads();
    const int wave = tid >> 6;
    const int lane = tid & 63;
#pragma unroll
    for (int j = 0; j < 8; ++j) {
      const int o = wave * 8 + j;
      const float* w = rw + (size_t)o * IN;
      float s0 = 0.f, s1 = 0.f, s2 = 0.f, s3 = 0.f;
      for (int i = 0; i < IN / 64; ++i) {           // 32 iters
        const float wv = w[lane + 64 * i];          // coalesced 256B
        s0 += sh[0 * IN + lane + 64 * i] * wv;
        s1 += sh[1 * IN + lane + 64 * i] * wv;
        s2 += sh[2 * IN + lane + 64 * i] * wv;
        s3 += sh[3 * IN + lane + 64 * i] * wv;
      }
#pragma unroll
      for (int d = 1; d < 64; d <<= 1) {
        s0 += __shfl_xor(s0, d);
        s1 += __shfl_xor(s1, d);
        s2 += __shfl_xor(s2, d);
        s3 += __shfl_xor(s3, d);
      }
      if (lane == 0) {
        const float bias = rb[o];
        rgT[o * B + b0 + 0] = 1.f / (1.f + expf(-(s0 + bias)));
        rgT[o * B + b0 + 1] = 1.f / (1.f + expf(-(s1 + bias)));
        rgT[o * B + b0 + 2] = 1.f / (1.f + expf(-(s2 + bias)));
        rgT[o * B + b0 + 3] = 1.f / (1.f + expf(-(s3 + bias)));
      }
    }
  } else {                                // --- binning (last), 4B entries ---
    const int i = (blk - TRX - TRH - RTR) * 512 + tid;
    if (i >= NTOT) return;
    int gc, r; float v;
    if (i < NNZ_W)              { gc = Wc[i];                 r = Wr[i]; v = Wv[i]; }
    else if (i < NNZ_W + NNZ_R) { int j = i - NNZ_W;          gc = HID + Rc[j];     r = Rr[j]; v = Rv[j]; }
    else                        { int j = i - NNZ_W - NNZ_R; gc = 2 * HID + Pc[j]; r = Pr[j]; v = Pv[j]; }
    const int p = atomicAdd(&cnt[gc], 1);
    packed[(size_t)gc * SLOT + p] = ((unsigned int)f2bf(v) << 16) | (unsigned int)(r & 0xFFFF);
  }
}

// ---------------------------------------------------------------------------
// Full-column bf16 gather, 4B meta entries: 8-batch meta = two uint4 loads.
// ---------------------------------------------------------------------------
__device__ __forceinline__ f8 gather_col_bf8(const unsigned short* __restrict__ srcb,
                                             const unsigned int* __restrict__ packed,
                                             int gc, int n, int boff, float bias) {
  f4 a0; a0.x = bias; a0.y = bias; a0.z = bias; a0.w = bias;
  f4 a1 = a0;
  const unsigned int* ep = packed + (size_t)gc * SLOT;
  int i = 0;
  for (; i + 8 <= n; i += 8) {
    const u4 e0 = *(const u4*)(ep + i);
    const u4 e1 = *(const u4*)(ep + i + 4);
    unsigned int e[8] = {e0.x, e0.y, e0.z, e0.w, e1.x, e1.y, e1.z, e1.w};
    us8 s[8];
#pragma unroll
    for (int j = 0; j < 8; ++j)
      s[j] = *(const us8*)(srcb + (size_t)(e[j] & 0xFFFFu) * B + boff);
#pragma unroll
    for (int j = 0; j < 8; ++j) {
      const float v = bf2f((unsigned short)(e[j] >> 16));
      a0.x += v * bf2f(s[j][0]); a0.y += v * bf2f(s[j][1]);
      a0.z += v * bf2f(s[j][2]); a0.w += v * bf2f(s[j][3]);
      a1.x += v * bf2f(s[j][4]); a1.y += v * bf2f(s[j][5]);
      a1.z += v * bf2f(s[j][6]); a1.w += v * bf2f(s[j][7]);
    }
  }
  for (; i < n; ++i) {
    const unsigned int e = ep[i];
    const us8 s = *(const us8*)(srcb + (size_t)(e & 0xFFFFu) * B + boff);
    const float v = bf2f((unsigned short)(e >> 16));
    a0.x += v * bf2f(s[0]); a0.y += v * bf2f(s[1]);
    a0.z += v * bf2f(s[2]); a0.w += v * bf2f(s[3]);
    a1.x += v * bf2f(s[4]); a1.y += v * bf2f(s[5]);
    a1.z += v * bf2f(s[6]); a1.w += v * bf2f(s[7]);
  }
  f8 r; r.lo = a0; r.hi = a1;
  return r;
}

// Epilogue: block's [4 c][512 b] tile -> row-major out (one f4/thread x 2 rows).
__device__ __forceinline__ void store_tile_T(float* __restrict__ tile,  // [4][512]
                                             const f8 v, int wave, int lane,
                                             int c0, float* __restrict__ out) {
  ((f4*)tile)[wave * 128 + lane * 2 + 0] = v.lo;
  ((f4*)tile)[wave * 128 + lane * 2 + 1] = v.hi;
  __syncthreads();
  const int t = threadIdx.x;              // 0..255
#pragma unroll
  for (int r = 0; r < 2; ++r) {
    const int b = r * 256 + t;
    f4 o;
    o.x = tile[0 * 512 + b];
    o.y = tile[1 * 512 + b];
    o.z = tile[2 * 512 + b];
    o.w = tile[3 * 512 + b];
    *(f4*)(out + (size_t)b * HID + c0) = o;
  }
}

// ---------------------------------------------------------------------------
// Fused: one wave per column; fp32 hT carry (r17 numerics).
// ---------------------------------------------------------------------------
__global__ void fused_gc_k(const unsigned short* __restrict__ xTb,
                           const unsigned short* __restrict__ hTb,
                           const float* __restrict__ hT,
                           const unsigned int* __restrict__ packed, const int* __restrict__ cnt,
                           const float* __restrict__ rgT,
                           const float* __restrict__ gate, const float* __restrict__ tau,
                           const float* __restrict__ wb, const float* __restrict__ rb,
                           float* __restrict__ out_h, unsigned short* __restrict__ hnb) {
  __shared__ float tile[4 * 512];
  const int wave = threadIdx.x >> 6, lane = threadIdx.x & 63;
  const int c0 = blockIdx.x * 4;
  const int c = c0 + wave;
  const int boff = lane * 8;

  const f8 sens = gather_col_bf8(xTb, packed, c, cnt[c], boff, wb[c]);
  const f8 rec  = gather_col_bf8(hTb, packed, HID + c, cnt[HID + c], boff, rb[c]);

  const float* rg = rgT + (size_t)(c >> 6) * B + boff;
  const f4 m0 = *(const f4*)rg;
  const f4 m1 = *(const f4*)(rg + 4);
  const f4 g0 = *(const f4*)(gate + boff);
  const f4 g1 = *(const f4*)(gate + boff + 4);
  const float* hpp = hT + (size_t)c * B + boff;
  const f4 hp0 = *(const f4*)hpp;
  const f4 hp1 = *(const f4*)(hpp + 4);
  const float k = DT / tau[c];

  f8 hn;
  hn.lo.x = hp0.x + g0.x * (tanhf(sens.lo.x * m0.x + rec.lo.x) - hp0.x) * k;
  hn.lo.y = hp0.y + g0.y * (tanhf(sens.lo.y * m0.y + rec.lo.y) - hp0.y) * k;
  hn.lo.z = hp0.z + g0.z * (tanhf(sens.lo.z * m0.z + rec.lo.z) - hp0.z) * k;
  hn.lo.w = hp0.w + g0.w * (tanhf(sens.lo.w * m0.w + rec.lo.w) - hp0.w) * k;
  hn.hi.x = hp1.x + g1.x * (tanhf(sens.hi.x * m1.x + rec.hi.x) - hp1.x) * k;
  hn.hi.y = hp1.y + g1.y * (tanhf(sens.hi.y * m1.y + rec.hi.y) - hp1.y) * k;
  hn.hi.z = hp1.z + g1.z * (tanhf(sens.hi.z * m1.z + rec.hi.z) - hp1.z) * k;
  hn.hi.w = hp1.w + g1.w * (tanhf(sens.hi.w * m1.w + rec.hi.w) - hp1.w) * k;

  us8 hb;
  hb[0] = f2bf(hn.lo.x); hb[1] = f2bf(hn.lo.y); hb[2] = f2bf(hn.lo.z); hb[3] = f2bf(hn.lo.w);
  hb[4] = f2bf(hn.hi.x); hb[5] = f2bf(hn.hi.y); hb[6] = f2bf(hn.hi.z); hb[7] = f2bf(hn.hi.w);
  *(us8*)(hnb + (size_t)c * B + boff) = hb;   // cached: pred's hot source

  store_tile_T(tile, hn, wave, lane, c0, out_h);
}

// ---------------------------------------------------------------------------
// Prediction: full-column waves from hnb, writes out_p.
// ---------------------------------------------------------------------------
__global__ void pred_k(const unsigned short* __restrict__ hnb,
                       const unsigned int* __restrict__ packed, const int* __restrict__ cnt,
                       const float* __restrict__ pb, float* __restrict__ out_p) {
  __shared__ float tile[4 * 512];
  const int wave = threadIdx.x >> 6, lane = threadIdx.x & 63;
  const int c0 = blockIdx.x * 4;
  const int c = c0 + wave;
  const int boff = lane * 8;
  const f8 p = gather_col_bf8(hnb, packed, 2 * HID + c, cnt[2 * HID + c], boff, pb[c]);
  store_tile_T(tile, p, wave, lane, c0, out_p);
}

}  // namespace

extern "C" void kernel_launch(void* const* d_in, const int* in_sizes, int n_in,
                              void* d_out, int out_size, void* d_ws, size_t ws_size,
                              hipStream_t stream) {
  const float* x        = (const float*)d_in[0];
  const float* h_prev   = (const float*)d_in[1];
  const float* gate     = (const float*)d_in[2];
  const float* W_vals   = (const float*)d_in[3];
  const float* W_bias   = (const float*)d_in[4];
  const float* R_vals   = (const float*)d_in[5];
  const float* R_bias   = (const float*)d_in[6];
  const float* P_vals   = (const float*)d_in[7];
  const float* P_bias   = (const float*)d_in[8];
  const float* router_w = (const float*)d_in[9];
  const float* router_b = (const float*)d_in[10];
  const float* tau      = (const float*)d_in[11];
  const int* W_rows = (const int*)d_in[12];
  const int* W_cols = (const int*)d_in[13];
  const int* R_rows = (const int*)d_in[14];
  const int* R_cols = (const int*)d_in[15];
  const int* P_rows = (const int*)d_in[16];
  const int* P_cols = (const int*)d_in[17];

  float* ws = (float*)d_ws;
  unsigned short* xTb = (unsigned short*)ws;                      // [IN][B]  bf16  2 MB
  float*  hT     = ws + (size_t)IN * B / 2;                       // [HID][B] f32   8 MB
  unsigned short* hTb = (unsigned short*)(hT + (size_t)HID * B);  // [HID][B] bf16  4 MB
  float*  rgT    = (float*)(hTb + (size_t)HID * B);               // [64][B]  f32
  unsigned short* hnb = (unsigned short*)(rgT + 64 * B);          // [HID][B] bf16  4 MB
  unsigned int* packed = (unsigned int*)(hnb + (size_t)HID * B);  // [NCOLS*SLOT] u32 6.3 MB
  int*    cnt    = (int*)(packed + (size_t)NCOLS * SLOT);         // [NCOLS]  48 KB

  float* out_h = (float*)d_out;
  float* out_p = out_h + (size_t)B * HID;

  // 1. Zero bucket counters (stream-ordered before binning atomics).
  hipMemsetAsync(cnt, 0, NCOLS * sizeof(int), stream);

  // 2. Merged prep (r17 role order + r17 router): transposes, router, binning.
  prep2_k<<<PREP2, 512, 0, stream>>>(x, xTb, h_prev, hT, hTb,
                                     router_w, router_b, rgT,
                                     W_cols, R_cols, P_cols,
                                     W_rows, R_rows, P_rows,
                                     W_vals, R_vals, P_vals, cnt, packed);

  // 3. Fused gather + integrate -> out_h (direct) + hnb.
  fused_gc_k<<<HID / 4, 256, 0, stream>>>(xTb, hTb, hT, packed, cnt, rgT,
                                          gate, tau, W_bias, R_bias, out_h, hnb);

  // 4. Prediction gather -> out_p (direct).
  pred_k<<<HID / 4, 256, 0, stream>>>(hnb, packed, cnt, P_bias, out_p);
}